// Round 1
// baseline (38495.453 us; speedup 1.0000x reference)
//
#include <hip/hip_runtime.h>
#include <stdint.h>

// AutoRegressiveModel: 47 outer x 512 inner sequential LSTM steps (mid=256),
// Bernoulli sampling must bit-match JAX threefry2x32 (partitionable mode).
//
// Persistent dataflow kernel: 17 blocks x 256 threads.
//   blocks 0..15 : LSTM workers. Block b owns h indices [16b,16b+16) i.e. the
//                  4 gate rows {j, 256+j, 512+j, 768+j}. W_hh slice (64 rows x
//                  256 cols = 16K weights) lives in VGPRs (64 fp32/thread).
//   block 16     : init + sampler (p = sigmoid(h.W_out+b), threefry RNG,
//                  logprob/entropy accumulation, obs feedback).
//
// Cross-block h exchange: self-tagged u64 words (float h | uint32 step) via
// device-scope relaxed atomics (bypass non-coherent per-XCD L2s). 4-slot
// rotating buffer for the recurrence; 512-deep history for the sampler, which
// trails the LSTM with up to 511 steps of slack (obs gate via p_prog flags).

#define MID      256
#define NOUT     48
#define NSEQ     512
#define NOUTER   47
#define NSTEP    (NOUTER * NSEQ)   // 24064
#define NBLK     16
#define HPER     16
#define MAGIC_V  0x1234ABCDu

__device__ __forceinline__ uint32_t rotl32(uint32_t x, int d) {
  return (x << d) | (x >> (32 - d));
}

// Exact JAX threefry2x32 (20 rounds).
__device__ __forceinline__ void threefry2x32(uint32_t k0, uint32_t k1,
                                             uint32_t x0, uint32_t x1,
                                             uint32_t& o0, uint32_t& o1) {
  uint32_t ks2 = k0 ^ k1 ^ 0x1BD11BDAu;
  uint32_t v0 = x0 + k0, v1 = x1 + k1;
#define TF_R(r) { v0 += v1; v1 = rotl32(v1, r); v1 ^= v0; }
  TF_R(13) TF_R(15) TF_R(26) TF_R(6)
  v0 += k1;  v1 += ks2 + 1u;
  TF_R(17) TF_R(29) TF_R(16) TF_R(24)
  v0 += ks2; v1 += k0 + 2u;
  TF_R(13) TF_R(15) TF_R(26) TF_R(6)
  v0 += k0;  v1 += k1 + 3u;
  TF_R(17) TF_R(29) TF_R(16) TF_R(24)
  v0 += k1;  v1 += ks2 + 4u;
  TF_R(13) TF_R(15) TF_R(26) TF_R(6)
  v0 += ks2; v1 += k0 + 5u;
#undef TF_R
  o0 = v0; o1 = v1;
}

__device__ __forceinline__ float sigf(float x) { return 1.0f / (1.0f + expf(-x)); }

__device__ __forceinline__ uint64_t packht(float h, uint32_t tag) {
  return ((uint64_t)tag << 32) | (uint64_t)__float_as_uint(h);
}

__global__ __launch_bounds__(256, 1)
void arlstm_kernel(const float* __restrict__ W_ih, const float* __restrict__ W_hh,
                   const float* __restrict__ b_ih, const float* __restrict__ b_hh,
                   const float* __restrict__ W_out, const float* __restrict__ b_out,
                   float* __restrict__ out, uint64_t* __restrict__ ws) {
  // ws layout (u64 units):
  uint64_t* h_slot = ws;                         // [4][256] tagged (rotating)
  uint64_t* h_hist = ws + 4 * 256;               // [512][256] tagged (history)
  float*    obsbuf = (float*)(ws + 4 * 256 + 512 * 256);  // [2][512][2]
  uint32_t* p_prog = (uint32_t*)(obsbuf + 2 * 512 * 2);   // [4] sampler progress
  uint32_t* magic  = p_prog + 16;

  const int tid = threadIdx.x;
  const int blk = blockIdx.x;

  __shared__ __align__(16) float hstage[256];
  __shared__ float plds[4][64];
  __shared__ float obs_lds[2];
  __shared__ float lp_acc[512];
  __shared__ float ent_acc[512];
  __shared__ float red[256];

  if (blk == NBLK) {
    // ----------------------- init + sampler block -----------------------
    __hip_atomic_store(&h_slot[tid], 0ull, __ATOMIC_RELAXED, __HIP_MEMORY_SCOPE_AGENT);
    if (tid < 16)
      __hip_atomic_store(&p_prog[tid], 0u, __ATOMIC_RELAXED, __HIP_MEMORY_SCOPE_AGENT);
    out[(tid)       * NOUT] = 0.0f;   // samples column 0 = zeros
    out[(tid + 256) * NOUT] = 0.0f;
    lp_acc[tid] = 0.0f;  lp_acc[tid + 256] = 0.0f;
    ent_acc[tid] = 0.0f; ent_acc[tid + 256] = 0.0f;
    __threadfence();
    __syncthreads();
    if (tid == 0)
      __hip_atomic_store(magic, MAGIC_V, __ATOMIC_RELEASE, __HIP_MEMORY_SCOPE_AGENT);

    const int w    = tid >> 6;   // wave 0..3 handles steps s with (s-1)&3 == w
    const int lane = tid & 63;
    const float wo0 = W_out[lane * 4 + 0], wo1 = W_out[lane * 4 + 1];
    const float wo2 = W_out[lane * 4 + 2], wo3 = W_out[lane * 4 + 3];
    const float bo = b_out[0];

    for (int s = w + 1; s <= NSTEP; s += 4) {
      const int k = (s - 1) >> 9;
      const int t = (s - 1) & 511;
      uint64_t* src = h_hist + (uint64_t)(s & 511) * 256 + lane * 4;
      uint64_t v0, v1, v2, v3;
      for (;;) {
        v0 = __hip_atomic_load(src + 0, __ATOMIC_RELAXED, __HIP_MEMORY_SCOPE_AGENT);
        v1 = __hip_atomic_load(src + 1, __ATOMIC_RELAXED, __HIP_MEMORY_SCOPE_AGENT);
        v2 = __hip_atomic_load(src + 2, __ATOMIC_RELAXED, __HIP_MEMORY_SCOPE_AGENT);
        v3 = __hip_atomic_load(src + 3, __ATOMIC_RELAXED, __HIP_MEMORY_SCOPE_AGENT);
        int ok = ((uint32_t)(v0 >> 32) == (uint32_t)s) &
                 ((uint32_t)(v1 >> 32) == (uint32_t)s) &
                 ((uint32_t)(v2 >> 32) == (uint32_t)s) &
                 ((uint32_t)(v3 >> 32) == (uint32_t)s);
        if (__all(ok)) break;
      }
      float zp = fmaf(__uint_as_float((uint32_t)v0), wo0,
                 fmaf(__uint_as_float((uint32_t)v1), wo1,
                 fmaf(__uint_as_float((uint32_t)v2), wo2,
                      __uint_as_float((uint32_t)v3) * wo3)));
      zp += __shfl_xor(zp, 1);
      zp += __shfl_xor(zp, 2);
      zp += __shfl_xor(zp, 4);
      zp += __shfl_xor(zp, 8);
      zp += __shfl_xor(zp, 16);
      zp += __shfl_xor(zp, 32);
      const float p = sigf(zp + bo);

      // JAX partitionable threefry: key_k = tf((0,42),(0,k)); bits = xor of
      // tf(key_k,(0,t)); u = bitcast((bits>>9)|0x3f800000)-1; sample = u < p.
      uint32_t ka, kb, c1, c2;
      threefry2x32(0u, 42u, 0u, (uint32_t)k, ka, kb);
      threefry2x32(ka, kb, 0u, (uint32_t)t, c1, c2);
      const uint32_t bits = c1 ^ c2;
      const float u = __uint_as_float((bits >> 9) | 0x3f800000u) - 1.0f;
      const float smp = (u < p) ? 1.0f : 0.0f;

      if (lane == 0) {
        uint32_t* ob = (uint32_t*)(obsbuf + ((k + 1) & 1) * (512 * 2) + t * 2);
        __hip_atomic_store(&ob[0], __float_as_uint(smp), __ATOMIC_RELAXED, __HIP_MEMORY_SCOPE_AGENT);
        __hip_atomic_store(&ob[1], __float_as_uint(p),   __ATOMIC_RELAXED, __HIP_MEMORY_SCOPE_AGENT);
        __hip_atomic_store(&p_prog[w], (uint32_t)s, __ATOMIC_RELEASE, __HIP_MEMORY_SCOPE_AGENT);
        out[t * NOUT + (k + 1)] = smp;
        const float lg = logf(p), lg1 = log1pf(-p);
        lp_acc[t]  += (smp > 0.5f) ? lg : lg1;
        ent_acc[t] -= (p * lg + (1.0f - p) * lg1);
      }
    }
    __syncthreads();
    // final outputs: logprobs (centered), entropies (mean over 47)
    red[tid] = lp_acc[tid] + lp_acc[tid + 256];
    __syncthreads();
    for (int off = 128; off > 0; off >>= 1) {
      if (tid < off) red[tid] += red[tid + off];
      __syncthreads();
    }
    const float mean = red[0] * (1.0f / 512.0f);
    out[24576 + tid]        = lp_acc[tid]        - mean;
    out[24576 + 256 + tid]  = lp_acc[tid + 256]  - mean;
    out[25088 + tid]        = ent_acc[tid]       * (1.0f / 47.0f);
    out[25088 + 256 + tid]  = ent_acc[tid + 256] * (1.0f / 47.0f);
  } else {
    // --------------------------- LSTM worker ---------------------------
    const int part = tid >> 6;          // column quarter 0..3
    const int r    = tid & 63;          // local row (gate*16 + jloc)
    const int gate = r >> 4;
    const int jloc = r & 15;
    const int row  = gate * 256 + blk * HPER + jloc;

    float wreg[64];
#pragma unroll
    for (int c = 0; c < 64; ++c)
      wreg[c] = W_hh[row * 256 + part * 64 + c];

    float bi[4], wx0[4], wx1[4];
    if (tid < 16) {
#pragma unroll
      for (int g4 = 0; g4 < 4; ++g4) {
        const int rr = g4 * 256 + blk * HPER + tid;
        bi[g4]  = b_ih[rr] + b_hh[rr];
        wx0[g4] = W_ih[rr * 2 + 0];
        wx1[g4] = W_ih[rr * 2 + 1];
      }
    }

    if (tid == 0) {
      while (__hip_atomic_load(magic, __ATOMIC_ACQUIRE, __HIP_MEMORY_SCOPE_AGENT) != MAGIC_V) {}
    }
    __syncthreads();

    float c_st = 0.0f;                      // cell state for h index jglob
    const int jglob = blk * HPER + (tid & 15);

    for (int s = 1; s <= NSTEP; ++s) {
      const int k = (s - 1) >> 9;
      const int t = (s - 1) & 511;

      float samp = 0.0f, pv = 0.0f;
      if (tid == 255 && k > 0) {
        const uint32_t X = (uint32_t)((k - 1) * 512 + t + 1);
        while (__hip_atomic_load(&p_prog[t & 3], __ATOMIC_ACQUIRE, __HIP_MEMORY_SCOPE_AGENT) < X) {}
        uint32_t* ob = (uint32_t*)(obsbuf + (k & 1) * (512 * 2) + t * 2);
        samp = __uint_as_float(__hip_atomic_load(&ob[0], __ATOMIC_RELAXED, __HIP_MEMORY_SCOPE_AGENT));
        pv   = __uint_as_float(__hip_atomic_load(&ob[1], __ATOMIC_RELAXED, __HIP_MEMORY_SCOPE_AGENT));
      }

      {  // spin on own self-tagged word of h_{s-1}
        uint64_t* src = h_slot + (uint64_t)((s - 1) & 3) * 256 + tid;
        uint64_t v;
        do {
          v = __hip_atomic_load(src, __ATOMIC_RELAXED, __HIP_MEMORY_SCOPE_AGENT);
        } while ((uint32_t)(v >> 32) != (uint32_t)(s - 1));
        hstage[tid] = __uint_as_float((uint32_t)v);
      }
      if (tid == 255) { obs_lds[0] = samp; obs_lds[1] = pv; }
      __syncthreads();

      float a0 = 0.f, a1 = 0.f, a2 = 0.f, a3 = 0.f;
      const float4* hs4 = (const float4*)(hstage + part * 64);
#pragma unroll
      for (int i = 0; i < 16; ++i) {
        const float4 hv = hs4[i];
        a0 = fmaf(wreg[4 * i + 0], hv.x, a0);
        a1 = fmaf(wreg[4 * i + 1], hv.y, a1);
        a2 = fmaf(wreg[4 * i + 2], hv.z, a2);
        a3 = fmaf(wreg[4 * i + 3], hv.w, a3);
      }
      plds[part][r] = (a0 + a1) + (a2 + a3);
      __syncthreads();

      if (tid < 16) {
        const float sx = obs_lds[0], px = obs_lds[1];
        float g[4];
#pragma unroll
        for (int g4 = 0; g4 < 4; ++g4) {
          const int rr = g4 * 16 + tid;
          const float base = wx0[g4] * sx + wx1[g4] * px + bi[g4];
          g[g4] = ((plds[0][rr] + plds[1][rr]) + (plds[2][rr] + plds[3][rr])) + base;
        }
        const float ig = sigf(g[0]);
        const float fg = sigf(g[1]);
        const float gg = tanhf(g[2]);
        const float og = sigf(g[3]);
        const float t1 = fg * c_st;
        const float t2 = ig * gg;
        c_st = t1 + t2;
        const float hnew = og * tanhf(c_st);
        const uint64_t pk = packht(hnew, (uint32_t)s);
        __hip_atomic_store(&h_slot[(uint64_t)(s & 3) * 256 + jglob], pk,
                           __ATOMIC_RELAXED, __HIP_MEMORY_SCOPE_AGENT);
        __hip_atomic_store(&h_hist[(uint64_t)(s & 511) * 256 + jglob], pk,
                           __ATOMIC_RELAXED, __HIP_MEMORY_SCOPE_AGENT);
      }
    }
  }
}

extern "C" void kernel_launch(void* const* d_in, const int* in_sizes, int n_in,
                              void* d_out, int out_size, void* d_ws, size_t ws_size,
                              hipStream_t stream) {
  const float* W_ih  = (const float*)d_in[0];
  const float* W_hh  = (const float*)d_in[1];
  const float* b_ih  = (const float*)d_in[2];
  const float* b_hh  = (const float*)d_in[3];
  const float* W_out = (const float*)d_in[4];
  const float* b_out = (const float*)d_in[5];
  float* out = (float*)d_out;
  uint64_t* ws = (uint64_t*)d_ws;

  arlstm_kernel<<<dim3(NBLK + 1), dim3(256), 0, stream>>>(
      W_ih, W_hh, b_ih, b_hh, W_out, b_out, out, ws);
}

// Round 2
// 31764.157 us; speedup vs baseline: 1.2119x; 1.2119x over previous
//
#include <hip/hip_runtime.h>
#include <stdint.h>

// AutoRegressiveModel: 47 outer x 512 inner sequential LSTM steps (mid=256),
// Bernoulli sampling bit-matches JAX threefry2x32 (partitionable mode).
//
// Persistent dataflow kernel: 17 blocks x 256 threads.
//   blocks 0..15 : LSTM workers. Block b owns h indices [16b,16b+16).
//                  W_hh slice (64 rows x 256 cols) in VGPRs (64 fp32/thread).
//   block 16     : init + sampler (p = sigmoid(h.W_out+b), threefry RNG,
//                  logprob/entropy accumulation, obs feedback).
//
// R2 changes vs R1 (38.5 ms):
//  - fast activations on the critical path: v_exp_f32 + v_rcp_f32
//    (tanh(x) = 2*sig(2x)-1, branchless, correct saturation)
//  - epilogue widened to 64 lanes (one gate per lane) + 3 __shfl gathers;
//    only one tanh left on the serial chain
//  - 2-deep pipelined spin poll (halves poll sampling period)
//  - h_slot merged into h_hist (single producer store; tags disambiguate)

#define MID      256
#define NOUT     48
#define NSEQ     512
#define NOUTER   47
#define NSTEP    (NOUTER * NSEQ)   // 24064
#define NBLK     16
#define MAGIC_V  0x1234ABCDu
#define LOG2E    1.4426950408889634f

__device__ __forceinline__ uint32_t rotl32(uint32_t x, int d) {
  return (x << d) | (x >> (32 - d));
}

// Exact JAX threefry2x32 (20 rounds).
__device__ __forceinline__ void threefry2x32(uint32_t k0, uint32_t k1,
                                             uint32_t x0, uint32_t x1,
                                             uint32_t& o0, uint32_t& o1) {
  uint32_t ks2 = k0 ^ k1 ^ 0x1BD11BDAu;
  uint32_t v0 = x0 + k0, v1 = x1 + k1;
#define TF_R(r) { v0 += v1; v1 = rotl32(v1, r); v1 ^= v0; }
  TF_R(13) TF_R(15) TF_R(26) TF_R(6)
  v0 += k1;  v1 += ks2 + 1u;
  TF_R(17) TF_R(29) TF_R(16) TF_R(24)
  v0 += ks2; v1 += k0 + 2u;
  TF_R(13) TF_R(15) TF_R(26) TF_R(6)
  v0 += k0;  v1 += k1 + 3u;
  TF_R(17) TF_R(29) TF_R(16) TF_R(24)
  v0 += k1;  v1 += ks2 + 4u;
  TF_R(13) TF_R(15) TF_R(26) TF_R(6)
  v0 += ks2; v1 += k0 + 5u;
#undef TF_R
  o0 = v0; o1 = v1;
}

// Accurate sigmoid for the sampler (off critical path).
__device__ __forceinline__ float sigf(float x) { return 1.0f / (1.0f + expf(-x)); }

__device__ __forceinline__ uint64_t packht(float h, uint32_t tag) {
  return ((uint64_t)tag << 32) | (uint64_t)__float_as_uint(h);
}

__global__ __launch_bounds__(256, 1)
void arlstm_kernel(const float* __restrict__ W_ih, const float* __restrict__ W_hh,
                   const float* __restrict__ b_ih, const float* __restrict__ b_hh,
                   const float* __restrict__ W_out, const float* __restrict__ b_out,
                   float* __restrict__ out, uint64_t* __restrict__ ws) {
  // ws layout (u64 units):
  uint64_t* h_hist = ws;                                  // [512][256] tagged
  float*    obsbuf = (float*)(ws + 512 * 256);            // [2][512][2]
  uint32_t* p_prog = (uint32_t*)(obsbuf + 2 * 512 * 2);   // [4] sampler progress
  uint32_t* magic  = p_prog + 16;

  const int tid = threadIdx.x;
  const int blk = blockIdx.x;

  __shared__ __align__(16) float hstage[256];
  __shared__ float plds[4][64];
  __shared__ float obs_lds[2];
  __shared__ float lp_acc[512];
  __shared__ float ent_acc[512];
  __shared__ float red[256];

  if (blk == NBLK) {
    // ----------------------- init + sampler block -----------------------
    // h_hist slot 0 holds h_0 = 0 with tag 0.
    __hip_atomic_store(&h_hist[tid], 0ull, __ATOMIC_RELAXED, __HIP_MEMORY_SCOPE_AGENT);
    if (tid < 16)
      __hip_atomic_store(&p_prog[tid], 0u, __ATOMIC_RELAXED, __HIP_MEMORY_SCOPE_AGENT);
    out[(tid)       * NOUT] = 0.0f;   // samples column 0 = zeros
    out[(tid + 256) * NOUT] = 0.0f;
    lp_acc[tid] = 0.0f;  lp_acc[tid + 256] = 0.0f;
    ent_acc[tid] = 0.0f; ent_acc[tid + 256] = 0.0f;
    __threadfence();
    __syncthreads();
    if (tid == 0)
      __hip_atomic_store(magic, MAGIC_V, __ATOMIC_RELEASE, __HIP_MEMORY_SCOPE_AGENT);

    const int w    = tid >> 6;   // wave 0..3 handles steps s with (s-1)&3 == w
    const int lane = tid & 63;
    const float wo0 = W_out[lane * 4 + 0], wo1 = W_out[lane * 4 + 1];
    const float wo2 = W_out[lane * 4 + 2], wo3 = W_out[lane * 4 + 3];
    const float bo = b_out[0];

    for (int s = w + 1; s <= NSTEP; s += 4) {
      const int k = (s - 1) >> 9;
      const int t = (s - 1) & 511;
      uint64_t* src = h_hist + (uint64_t)(s & 511) * 256 + lane * 4;
      uint64_t v0, v1, v2, v3;
      for (;;) {
        v0 = __hip_atomic_load(src + 0, __ATOMIC_RELAXED, __HIP_MEMORY_SCOPE_AGENT);
        v1 = __hip_atomic_load(src + 1, __ATOMIC_RELAXED, __HIP_MEMORY_SCOPE_AGENT);
        v2 = __hip_atomic_load(src + 2, __ATOMIC_RELAXED, __HIP_MEMORY_SCOPE_AGENT);
        v3 = __hip_atomic_load(src + 3, __ATOMIC_RELAXED, __HIP_MEMORY_SCOPE_AGENT);
        int ok = ((uint32_t)(v0 >> 32) == (uint32_t)s) &
                 ((uint32_t)(v1 >> 32) == (uint32_t)s) &
                 ((uint32_t)(v2 >> 32) == (uint32_t)s) &
                 ((uint32_t)(v3 >> 32) == (uint32_t)s);
        if (__all(ok)) break;
      }
      float zp = fmaf(__uint_as_float((uint32_t)v0), wo0,
                 fmaf(__uint_as_float((uint32_t)v1), wo1,
                 fmaf(__uint_as_float((uint32_t)v2), wo2,
                      __uint_as_float((uint32_t)v3) * wo3)));
      zp += __shfl_xor(zp, 1);
      zp += __shfl_xor(zp, 2);
      zp += __shfl_xor(zp, 4);
      zp += __shfl_xor(zp, 8);
      zp += __shfl_xor(zp, 16);
      zp += __shfl_xor(zp, 32);
      const float p = sigf(zp + bo);

      // JAX partitionable threefry: key_k = tf((0,42),(0,k)); bits = xor of
      // tf(key_k,(0,t)); u = bitcast((bits>>9)|0x3f800000)-1; sample = u < p.
      uint32_t ka, kb, c1, c2;
      threefry2x32(0u, 42u, 0u, (uint32_t)k, ka, kb);
      threefry2x32(ka, kb, 0u, (uint32_t)t, c1, c2);
      const uint32_t bits = c1 ^ c2;
      const float u = __uint_as_float((bits >> 9) | 0x3f800000u) - 1.0f;
      const float smp = (u < p) ? 1.0f : 0.0f;

      if (lane == 0) {
        uint32_t* ob = (uint32_t*)(obsbuf + ((k + 1) & 1) * (512 * 2) + t * 2);
        __hip_atomic_store(&ob[0], __float_as_uint(smp), __ATOMIC_RELAXED, __HIP_MEMORY_SCOPE_AGENT);
        __hip_atomic_store(&ob[1], __float_as_uint(p),   __ATOMIC_RELAXED, __HIP_MEMORY_SCOPE_AGENT);
        __hip_atomic_store(&p_prog[w], (uint32_t)s, __ATOMIC_RELEASE, __HIP_MEMORY_SCOPE_AGENT);
        out[t * NOUT + (k + 1)] = smp;
        const float lg = logf(p), lg1 = log1pf(-p);
        lp_acc[t]  += (smp > 0.5f) ? lg : lg1;
        ent_acc[t] -= (p * lg + (1.0f - p) * lg1);
      }
    }
    __syncthreads();
    // final outputs: logprobs (centered), entropies (mean over 47)
    red[tid] = lp_acc[tid] + lp_acc[tid + 256];
    __syncthreads();
    for (int off = 128; off > 0; off >>= 1) {
      if (tid < off) red[tid] += red[tid + off];
      __syncthreads();
    }
    const float mean = red[0] * (1.0f / 512.0f);
    out[24576 + tid]        = lp_acc[tid]        - mean;
    out[24576 + 256 + tid]  = lp_acc[tid + 256]  - mean;
    out[25088 + tid]        = ent_acc[tid]       * (1.0f / 47.0f);
    out[25088 + 256 + tid]  = ent_acc[tid + 256] * (1.0f / 47.0f);
  } else {
    // --------------------------- LSTM worker ---------------------------
    const int part = tid >> 6;          // column quarter 0..3
    const int r    = tid & 63;          // local row (gate*16 + jloc)
    const int gate = r >> 4;
    const int jloc = r & 15;
    const int row  = gate * 256 + blk * 16 + jloc;

    float wreg[64];
#pragma unroll
    for (int c = 0; c < 64; ++c)
      wreg[c] = W_hh[row * 256 + part * 64 + c];

    // Per-lane epilogue constants (lanes 0..63: lane = gate*16 + j).
    float bb = 0.f, wx0 = 0.f, wx1 = 0.f, mconst = 0.f, ml = 0.f, ad = 0.f;
    if (tid < 64) {
      const int g4 = tid >> 4;
      const int rr = g4 * 256 + blk * 16 + (tid & 15);
      bb  = b_ih[rr] + b_hh[rr];
      wx0 = W_ih[rr * 2 + 0];
      wx1 = W_ih[rr * 2 + 1];
      mconst = (g4 == 2) ? (-2.0f * LOG2E) : (-LOG2E);  // act = ml*sig(sc*x)+ad
      ml     = (g4 == 2) ? 2.0f : 1.0f;
      ad     = (g4 == 2) ? -1.0f : 0.0f;
    }

    if (tid == 0) {
      while (__hip_atomic_load(magic, __ATOMIC_ACQUIRE, __HIP_MEMORY_SCOPE_AGENT) != MAGIC_V) {}
    }
    __syncthreads();

    float c_st = 0.0f;                      // cell state (lanes 0..15)
    const int jglob = blk * 16 + (tid & 15);

    for (int s = 1; s <= NSTEP; ++s) {
      const int k = (s - 1) >> 9;
      const int t = (s - 1) & 511;

      float samp = 0.0f, pv = 0.0f;
      if (tid == 255 && k > 0) {
        const uint32_t X = (uint32_t)((k - 1) * 512 + t + 1);
        while (__hip_atomic_load(&p_prog[t & 3], __ATOMIC_ACQUIRE, __HIP_MEMORY_SCOPE_AGENT) < X) {}
        uint32_t* ob = (uint32_t*)(obsbuf + (k & 1) * (512 * 2) + t * 2);
        samp = __uint_as_float(__hip_atomic_load(&ob[0], __ATOMIC_RELAXED, __HIP_MEMORY_SCOPE_AGENT));
        pv   = __uint_as_float(__hip_atomic_load(&ob[1], __ATOMIC_RELAXED, __HIP_MEMORY_SCOPE_AGENT));
      }

      {  // 2-deep pipelined spin on own self-tagged word of h_{s-1}
        uint64_t* src = h_hist + (uint64_t)((s - 1) & 511) * 256 + tid;
        const uint32_t want = (uint32_t)(s - 1);
        uint64_t v = __hip_atomic_load(src, __ATOMIC_RELAXED, __HIP_MEMORY_SCOPE_AGENT);
        if ((uint32_t)(v >> 32) != want) {
          uint64_t a = __hip_atomic_load(src, __ATOMIC_RELAXED, __HIP_MEMORY_SCOPE_AGENT);
          uint64_t b = __hip_atomic_load(src, __ATOMIC_RELAXED, __HIP_MEMORY_SCOPE_AGENT);
          for (;;) {
            if ((uint32_t)(a >> 32) == want) { v = a; break; }
            a = __hip_atomic_load(src, __ATOMIC_RELAXED, __HIP_MEMORY_SCOPE_AGENT);
            if ((uint32_t)(b >> 32) == want) { v = b; break; }
            b = __hip_atomic_load(src, __ATOMIC_RELAXED, __HIP_MEMORY_SCOPE_AGENT);
          }
        }
        hstage[tid] = __uint_as_float((uint32_t)v);
      }
      if (tid == 255) { obs_lds[0] = samp; obs_lds[1] = pv; }
      __syncthreads();

      float a0 = 0.f, a1 = 0.f, a2 = 0.f, a3 = 0.f;
      const float4* hs4 = (const float4*)(hstage + part * 64);
#pragma unroll
      for (int i = 0; i < 16; ++i) {
        const float4 hv = hs4[i];
        a0 = fmaf(wreg[4 * i + 0], hv.x, a0);
        a1 = fmaf(wreg[4 * i + 1], hv.y, a1);
        a2 = fmaf(wreg[4 * i + 2], hv.z, a2);
        a3 = fmaf(wreg[4 * i + 3], hv.w, a3);
      }
      plds[part][r] = (a0 + a1) + (a2 + a3);
      __syncthreads();

      if (tid < 64) {
        // One gate per lane: gv = full gate pre-activation.
        const float sx = obs_lds[0], px = obs_lds[1];
        const float base = wx0 * sx + wx1 * px + bb;
        const float gv = ((plds[0][tid] + plds[1][tid]) +
                          (plds[2][tid] + plds[3][tid])) + base;
        // act = sig(gv) for gates i,f,o; tanh(gv) = 2*sig(2gv)-1 for gate g.
        const float e   = __builtin_amdgcn_exp2f(gv * mconst);
        const float y   = __builtin_amdgcn_rcpf(1.0f + e);
        const float act = __builtin_fmaf(ml, y, ad);
        const int j = tid & 15;
        const float a_f = __shfl(act, j + 16, 64);
        const float a_g = __shfl(act, j + 32, 64);
        const float a_o = __shfl(act, j + 48, 64);
        if (tid < 16) {
          const float t1 = a_f * c_st;
          const float t2 = act * a_g;     // act = sig(i) on lanes 0..15
          c_st = t1 + t2;
          const float ec = __builtin_amdgcn_exp2f(c_st * (-2.0f * LOG2E));
          const float yc = __builtin_amdgcn_rcpf(1.0f + ec);
          const float th = __builtin_fmaf(2.0f, yc, -1.0f);
          const float hnew = a_o * th;
          __hip_atomic_store(&h_hist[(uint64_t)(s & 511) * 256 + jglob],
                             packht(hnew, (uint32_t)s),
                             __ATOMIC_RELAXED, __HIP_MEMORY_SCOPE_AGENT);
        }
      }
    }
  }
}

extern "C" void kernel_launch(void* const* d_in, const int* in_sizes, int n_in,
                              void* d_out, int out_size, void* d_ws, size_t ws_size,
                              hipStream_t stream) {
  const float* W_ih  = (const float*)d_in[0];
  const float* W_hh  = (const float*)d_in[1];
  const float* b_ih  = (const float*)d_in[2];
  const float* b_hh  = (const float*)d_in[3];
  const float* W_out = (const float*)d_in[4];
  const float* b_out = (const float*)d_in[5];
  float* out = (float*)d_out;
  uint64_t* ws = (uint64_t*)d_ws;

  arlstm_kernel<<<dim3(NBLK + 1), dim3(256), 0, stream>>>(
      W_ih, W_hh, b_ih, b_hh, W_out, b_out, out, ws);
}